// Round 1
// baseline (709.520 us; speedup 1.0000x reference)
//
#include <hip/hip_runtime.h>
#include <hip/hip_bf16.h>
#include <stdint.h>

#define Bx 4
#define Tx 2048
#define Cx 1024
#define Hx 16
#define Dx 64
#define Mx (Bx*Tx)

typedef __bf16 bf16x8 __attribute__((ext_vector_type(8)));
typedef float f32x4 __attribute__((ext_vector_type(4)));
typedef unsigned short u16x8 __attribute__((ext_vector_type(8)));

__device__ __forceinline__ unsigned short f2bf(float f) {
  union { float f; unsigned u; } v; v.f = f;
  unsigned r = v.u + 0x7fffu + ((v.u >> 16) & 1u);
  return (unsigned short)(r >> 16);
}

// ---------------- f32 -> bf16 convert (vectorized, 8 elems/thread) -------------
__global__ void cvt_kernel(const float* __restrict__ in, unsigned short* __restrict__ out, int n) {
  int i = blockIdx.x * blockDim.x + threadIdx.x;
  int idx = i << 3;
  if (idx >= n) return;
  const float4* p = (const float4*)(in + idx);
  float4 a = p[0], b = p[1];
  u16x8 o;
  o[0] = f2bf(a.x); o[1] = f2bf(a.y); o[2] = f2bf(a.z); o[3] = f2bf(a.w);
  o[4] = f2bf(b.x); o[5] = f2bf(b.y); o[6] = f2bf(b.z); o[7] = f2bf(b.w);
  *(u16x8*)(out + idx) = o;
}

// ---------------- NT GEMM: C[M][N] = A[M][K] * B[N][K]^T, bf16 in, f32 acc ------
// m97 structure: 128x128 tile, BK=32, 4 waves (2x2), global_load_lds width 16.
#define GLOAD_LDS16(g, l) \
  __builtin_amdgcn_global_load_lds((const __attribute__((address_space(1))) void*)(g), \
                                   (__attribute__((address_space(3))) void*)(l), 16, 0, 0)

template<int OUT_F32>
__global__ __launch_bounds__(256) void gemm_nt(const unsigned short* __restrict__ A,
                                               const unsigned short* __restrict__ Bm,
                                               void* __restrict__ Cv,
                                               int M, int N, int K)
{
  __shared__ unsigned short As[128 * 32];
  __shared__ unsigned short Bs[128 * 32];
  const int tid  = threadIdx.x;
  const int wave = tid >> 6, lane = tid & 63;
  const int l15 = lane & 15, l4 = lane >> 4;
  const int mBase = blockIdx.y << 7;
  const int nBase = blockIdx.x << 7;
  const int wm = wave >> 1, wn = wave & 1;

  // staging map: elem e = call*2048 + wave*512 + lane*8 -> row = e/32, k = e%32 (linear LDS!)
  const int srow  = (wave << 4) + (lane >> 2);
  const int skcol = (lane & 3) << 3;

  f32x4 acc[4][4];
  #pragma unroll
  for (int i = 0; i < 4; ++i)
    #pragma unroll
    for (int j = 0; j < 4; ++j) { acc[i][j][0] = 0.f; acc[i][j][1] = 0.f; acc[i][j][2] = 0.f; acc[i][j][3] = 0.f; }

  const unsigned short* aRow = A  + (size_t)(mBase + srow) * K + skcol;
  const unsigned short* bRow = Bm + (size_t)(nBase + srow) * K + skcol;
  unsigned short* aL0 = As + (wave << 9);
  unsigned short* bL0 = Bs + (wave << 9);

  for (int k0 = 0; k0 < K; k0 += 32) {
    GLOAD_LDS16(aRow + k0,                   aL0);
    GLOAD_LDS16(aRow + (size_t)64 * K + k0,  aL0 + 2048);
    GLOAD_LDS16(bRow + k0,                   bL0);
    GLOAD_LDS16(bRow + (size_t)64 * K + k0,  bL0 + 2048);
    __syncthreads();   // compiler drains vmcnt before barrier -> staged data visible

    bf16x8 af[4], bfr[4];
    #pragma unroll
    for (int mi = 0; mi < 4; ++mi)
      af[mi] = *(const bf16x8*)&As[((wm << 6) + (mi << 4) + l15) * 32 + (l4 << 3)];
    #pragma unroll
    for (int nj = 0; nj < 4; ++nj)
      bfr[nj] = *(const bf16x8*)&Bs[((wn << 6) + (nj << 4) + l15) * 32 + (l4 << 3)];
    #pragma unroll
    for (int mi = 0; mi < 4; ++mi)
      #pragma unroll
      for (int nj = 0; nj < 4; ++nj)
        acc[mi][nj] = __builtin_amdgcn_mfma_f32_16x16x32_bf16(af[mi], bfr[nj], acc[mi][nj], 0, 0, 0);
    __syncthreads();   // protect LDS from next-iter staging
  }

  #pragma unroll
  for (int mi = 0; mi < 4; ++mi) {
    #pragma unroll
    for (int nj = 0; nj < 4; ++nj) {
      const int row = mBase + (wm << 6) + (mi << 4) + (l4 << 2);
      const int col = nBase + (wn << 6) + (nj << 4) + l15;
      #pragma unroll
      for (int r = 0; r < 4; ++r) {
        float v = acc[mi][nj][r];
        if (OUT_F32) ((float*)Cv)[(size_t)(row + r) * N + col] = v;
        else ((unsigned short*)Cv)[(size_t)(row + r) * N + col] = f2bf(v);
      }
    }
  }
}

// ---------------- V transpose: qkv[...,2048+h*64+d] -> vt[b,h,d,t] ---------------
__global__ void vtrans_kernel(const unsigned short* __restrict__ qkv, unsigned short* __restrict__ vt) {
  const int bh = blockIdx.y;
  const int b = bh >> 4, h = bh & 15;
  const int t0 = blockIdx.x << 6;
  __shared__ unsigned short tile[64][65];
  const int tid = threadIdx.x;
  const unsigned short* src = qkv + (size_t)b * Tx * 3072 + 2048 + h * 64;
  for (int e = tid; e < 4096; e += 256) {
    int r = e >> 6, c = e & 63;
    tile[c][r] = src[(size_t)(t0 + r) * 3072 + c];
  }
  __syncthreads();
  unsigned short* dst = vt + (size_t)bh * 64 * Tx + t0;
  for (int e = tid; e < 4096; e += 256) {
    int d = e >> 6, tt = e & 63;
    dst[(size_t)d * Tx + tt] = tile[d][tt];
  }
}

// ---------------- causal flash attention -----------------------------------------
// grid (32 qblocks, 64 bh), 256 thr = 4 waves, wave owns 16 q rows. KVBLK=64.
__global__ __launch_bounds__(256) void attn_kernel(const unsigned short* __restrict__ qkv,
                                                   const unsigned short* __restrict__ vt,
                                                   unsigned short* __restrict__ aout)
{
  const int qblk = (int)(gridDim.x - 1) - (int)blockIdx.x;  // heavy blocks first
  const int bh = blockIdx.y;
  const int b = bh >> 4, h = bh & 15;
  const int wave = threadIdx.x >> 6, lane = threadIdx.x & 63;
  const int l15 = lane & 15, l4 = lane >> 4;
  const int qrow0 = (qblk << 6) + (wave << 4);

  const unsigned short* qp = qkv + (size_t)b * Tx * 3072 + h * 64;
  const unsigned short* kp = qp + 1024;
  const unsigned short* vp = vt + (size_t)bh * 64 * Tx;

  __shared__ unsigned short Pl[4][16 * 72];  // per-wave P tile, padded rows (144B = 16*9)

  bf16x8 aq[2];
  aq[0] = *(const bf16x8*)&qp[(size_t)(qrow0 + l15) * 3072 + (l4 << 3)];
  aq[1] = *(const bf16x8*)&qp[(size_t)(qrow0 + l15) * 3072 + 32 + (l4 << 3)];

  float m_run[4], l_run[4];
  f32x4 oacc[4];
  #pragma unroll
  for (int r = 0; r < 4; ++r) { m_run[r] = -3.0e38f; l_run[r] = 0.f; }
  #pragma unroll
  for (int nt = 0; nt < 4; ++nt) { oacc[nt][0] = 0.f; oacc[nt][1] = 0.f; oacc[nt][2] = 0.f; oacc[nt][3] = 0.f; }

  for (int kvt = 0; kvt <= qblk; ++kvt) {
    const int kv0 = kvt << 6;
    // ---- S = Q K^T ----
    f32x4 s[4];
    #pragma unroll
    for (int nt = 0; nt < 4; ++nt) { s[nt][0] = 0.f; s[nt][1] = 0.f; s[nt][2] = 0.f; s[nt][3] = 0.f; }
    #pragma unroll
    for (int nt = 0; nt < 4; ++nt) {
      const unsigned short* krow = &kp[(size_t)(kv0 + (nt << 4) + l15) * 3072 + (l4 << 3)];
      bf16x8 bk0 = *(const bf16x8*)krow;
      bf16x8 bk1 = *(const bf16x8*)(krow + 32);
      s[nt] = __builtin_amdgcn_mfma_f32_16x16x32_bf16(aq[0], bk0, s[nt], 0, 0, 0);
      s[nt] = __builtin_amdgcn_mfma_f32_16x16x32_bf16(aq[1], bk1, s[nt], 0, 0, 0);
    }
    // ---- scale + causal mask (only diagonal tile) ----
    const bool diag = (kvt == qblk);
    float pv[4][4];
    #pragma unroll
    for (int nt = 0; nt < 4; ++nt) {
      const int kv = kv0 + (nt << 4) + l15;
      #pragma unroll
      for (int r = 0; r < 4; ++r) {
        float val = s[nt][r] * 0.125f;
        if (diag && kv > qrow0 + (l4 << 2) + r) val = -3.0e38f;
        pv[nt][r] = val;
      }
    }
    // ---- online softmax (wave-parallel: reduce over 16 lanes sharing l4) ----
    float pm[4];
    #pragma unroll
    for (int r = 0; r < 4; ++r)
      pm[r] = fmaxf(fmaxf(pv[0][r], pv[1][r]), fmaxf(pv[2][r], pv[3][r]));
    #pragma unroll
    for (int off = 1; off < 16; off <<= 1) {
      #pragma unroll
      for (int r = 0; r < 4; ++r) pm[r] = fmaxf(pm[r], __shfl_xor(pm[r], off));
    }
    float corr[4];
    #pragma unroll
    for (int r = 0; r < 4; ++r) {
      float mnew = fmaxf(m_run[r], pm[r]);
      corr[r] = __expf(m_run[r] - mnew);
      m_run[r] = mnew;
    }
    float rs[4] = {0.f, 0.f, 0.f, 0.f};
    #pragma unroll
    for (int nt = 0; nt < 4; ++nt)
      #pragma unroll
      for (int r = 0; r < 4; ++r) {
        float p = __expf(pv[nt][r] - m_run[r]);
        pv[nt][r] = p;
        rs[r] += p;
      }
    #pragma unroll
    for (int off = 1; off < 16; off <<= 1) {
      #pragma unroll
      for (int r = 0; r < 4; ++r) rs[r] += __shfl_xor(rs[r], off);
    }
    #pragma unroll
    for (int r = 0; r < 4; ++r) l_run[r] = l_run[r] * corr[r] + rs[r];
    #pragma unroll
    for (int nt = 0; nt < 4; ++nt)
      #pragma unroll
      for (int r = 0; r < 4; ++r) oacc[nt][r] *= corr[r];

    // ---- P -> LDS (bf16), then PV ----
    __syncthreads();  // prev iter's P reads complete everywhere
    #pragma unroll
    for (int nt = 0; nt < 4; ++nt)
      #pragma unroll
      for (int r = 0; r < 4; ++r)
        Pl[wave][((l4 << 2) + r) * 72 + (nt << 4) + l15] = f2bf(pv[nt][r]);
    __syncthreads();  // writes visible

    bf16x8 ap0 = *(const bf16x8*)&Pl[wave][l15 * 72 + (l4 << 3)];
    bf16x8 ap1 = *(const bf16x8*)&Pl[wave][l15 * 72 + 32 + (l4 << 3)];
    #pragma unroll
    for (int nt = 0; nt < 4; ++nt) {
      const unsigned short* vrow = &vp[(size_t)((nt << 4) + l15) * Tx + kv0 + (l4 << 3)];
      bf16x8 bv0 = *(const bf16x8*)vrow;
      bf16x8 bv1 = *(const bf16x8*)(vrow + 32);
      oacc[nt] = __builtin_amdgcn_mfma_f32_16x16x32_bf16(ap0, bv0, oacc[nt], 0, 0, 0);
      oacc[nt] = __builtin_amdgcn_mfma_f32_16x16x32_bf16(ap1, bv1, oacc[nt], 0, 0, 0);
    }
  }

  // ---- epilogue: divide by l, store attn_out[b,t,h*64+d] bf16 ----
  unsigned short* op = aout + (size_t)b * Tx * 1024 + h * 64;
  #pragma unroll
  for (int r = 0; r < 4; ++r) {
    const float inv = 1.0f / l_run[r];
    #pragma unroll
    for (int nt = 0; nt < 4; ++nt)
      op[(size_t)(qrow0 + (l4 << 2) + r) * 1024 + (nt << 4) + l15] = f2bf(oacc[nt][r] * inv);
  }
}

// ---------------- launch ----------------------------------------------------------
extern "C" void kernel_launch(void* const* d_in, const int* in_sizes, int n_in,
                              void* d_out, int out_size, void* d_ws, size_t ws_size,
                              hipStream_t stream) {
  const float* x     = (const float*)d_in[0];
  const float* wqkv  = (const float*)d_in[1];
  const float* wproj = (const float*)d_in[2];

  char* ws = (char*)d_ws;
  // layout (bytes): qkvb 50331648 | vtb 16777216 | xb/aob 16777216 | wqb 6291456 | wpb 2097152
  unsigned short* qkvb = (unsigned short*)(ws);
  unsigned short* vtb  = (unsigned short*)(ws + 50331648);
  unsigned short* xb   = (unsigned short*)(ws + 50331648 + 16777216);
  unsigned short* wqb  = (unsigned short*)(ws + 50331648 + 16777216 + 16777216);
  unsigned short* wpb  = (unsigned short*)(ws + 50331648 + 16777216 + 16777216 + 6291456);
  unsigned short* aob  = xb;  // alias: xb dead after GEMM1

  cvt_kernel<<<4096, 256, 0, stream>>>(x,     xb,  Bx * Tx * Cx);
  cvt_kernel<<<1536, 256, 0, stream>>>(wqkv,  wqb, 3 * Cx * Cx);
  cvt_kernel<<<512,  256, 0, stream>>>(wproj, wpb, Cx * Cx);

  gemm_nt<0><<<dim3(24, 64), 256, 0, stream>>>(xb, wqb, qkvb, Mx, 3072, 1024);
  vtrans_kernel<<<dim3(32, 64), 256, 0, stream>>>(qkvb, vtb);
  attn_kernel<<<dim3(32, 64), 256, 0, stream>>>(qkvb, vtb, aob);
  gemm_nt<1><<<dim3(8, 64), 256, 0, stream>>>(aob, wpb, d_out, Mx, 1024, 1024);
}

// Round 2
// 448.471 us; speedup vs baseline: 1.5821x; 1.5821x over previous
//
#include <hip/hip_runtime.h>
#include <hip/hip_bf16.h>
#include <stdint.h>

#define Bx 4
#define Tx 2048
#define Cx 1024
#define Hx 16
#define Dx 64
#define Mx (Bx*Tx)

typedef __bf16 bf16x8 __attribute__((ext_vector_type(8)));
typedef float f32x4 __attribute__((ext_vector_type(4)));
typedef unsigned short u16x8 __attribute__((ext_vector_type(8)));

__device__ __forceinline__ unsigned short f2bf(float f) {
  union { float f; unsigned u; } v; v.f = f;
  unsigned r = v.u + 0x7fffu + ((v.u >> 16) & 1u);
  return (unsigned short)(r >> 16);
}

// ---------------- f32 -> bf16 convert (vectorized, 8 elems/thread) -------------
__global__ void cvt_kernel(const float* __restrict__ in, unsigned short* __restrict__ out, int n) {
  int i = blockIdx.x * blockDim.x + threadIdx.x;
  int idx = i << 3;
  if (idx >= n) return;
  const float4* p = (const float4*)(in + idx);
  float4 a = p[0], b = p[1];
  u16x8 o;
  o[0] = f2bf(a.x); o[1] = f2bf(a.y); o[2] = f2bf(a.z); o[3] = f2bf(a.w);
  o[4] = f2bf(b.x); o[5] = f2bf(b.y); o[6] = f2bf(b.z); o[7] = f2bf(b.w);
  *(u16x8*)(out + idx) = o;
}

// ---------------- NT GEMM: C[M][N] = A[M][K] * B[N][K]^T, bf16 in, f32 acc ------
#define GLOAD_LDS16(g, l) \
  __builtin_amdgcn_global_load_lds((const __attribute__((address_space(1))) void*)(g), \
                                   (__attribute__((address_space(3))) void*)(l), 16, 0, 0)

template<int OUT_F32>
__global__ __launch_bounds__(256) void gemm_nt(const unsigned short* __restrict__ A,
                                               const unsigned short* __restrict__ Bm,
                                               void* __restrict__ Cv,
                                               int M, int N, int K)
{
  __shared__ unsigned short As[128 * 32];
  __shared__ unsigned short Bs[128 * 32];
  const int tid  = threadIdx.x;
  const int wave = tid >> 6, lane = tid & 63;
  const int l15 = lane & 15, l4 = lane >> 4;
  const int mBase = blockIdx.y << 7;
  const int nBase = blockIdx.x << 7;
  const int wm = wave >> 1, wn = wave & 1;

  const int srow  = (wave << 4) + (lane >> 2);
  const int skcol = (lane & 3) << 3;

  f32x4 acc[4][4];
  #pragma unroll
  for (int i = 0; i < 4; ++i)
    #pragma unroll
    for (int j = 0; j < 4; ++j) { acc[i][j][0] = 0.f; acc[i][j][1] = 0.f; acc[i][j][2] = 0.f; acc[i][j][3] = 0.f; }

  const unsigned short* aRow = A  + (size_t)(mBase + srow) * K + skcol;
  const unsigned short* bRow = Bm + (size_t)(nBase + srow) * K + skcol;
  unsigned short* aL0 = As + (wave << 9);
  unsigned short* bL0 = Bs + (wave << 9);

  for (int k0 = 0; k0 < K; k0 += 32) {
    GLOAD_LDS16(aRow + k0,                   aL0);
    GLOAD_LDS16(aRow + (size_t)64 * K + k0,  aL0 + 2048);
    GLOAD_LDS16(bRow + k0,                   bL0);
    GLOAD_LDS16(bRow + (size_t)64 * K + k0,  bL0 + 2048);
    __syncthreads();

    bf16x8 af[4], bfr[4];
    #pragma unroll
    for (int mi = 0; mi < 4; ++mi)
      af[mi] = *(const bf16x8*)&As[((wm << 6) + (mi << 4) + l15) * 32 + (l4 << 3)];
    #pragma unroll
    for (int nj = 0; nj < 4; ++nj)
      bfr[nj] = *(const bf16x8*)&Bs[((wn << 6) + (nj << 4) + l15) * 32 + (l4 << 3)];
    #pragma unroll
    for (int mi = 0; mi < 4; ++mi)
      #pragma unroll
      for (int nj = 0; nj < 4; ++nj)
        acc[mi][nj] = __builtin_amdgcn_mfma_f32_16x16x32_bf16(af[mi], bfr[nj], acc[mi][nj], 0, 0, 0);
    __syncthreads();
  }

  #pragma unroll
  for (int mi = 0; mi < 4; ++mi) {
    #pragma unroll
    for (int nj = 0; nj < 4; ++nj) {
      const int row = mBase + (wm << 6) + (mi << 4) + (l4 << 2);
      const int col = nBase + (wn << 6) + (nj << 4) + l15;
      #pragma unroll
      for (int r = 0; r < 4; ++r) {
        float v = acc[mi][nj][r];
        if (OUT_F32) ((float*)Cv)[(size_t)(row + r) * N + col] = v;
        else ((unsigned short*)Cv)[(size_t)(row + r) * N + col] = f2bf(v);
      }
    }
  }
}

// ---------------- V transpose: qkv[...,2048+h*64+d] -> vt[b,h,d,t] ---------------
__global__ void vtrans_kernel(const unsigned short* __restrict__ qkv, unsigned short* __restrict__ vt) {
  const int bh = blockIdx.y;
  const int b = bh >> 4, h = bh & 15;
  const int t0 = blockIdx.x << 6;
  __shared__ unsigned short tile[64][65];
  const int tid = threadIdx.x;
  const unsigned short* src = qkv + (size_t)b * Tx * 3072 + 2048 + h * 64;
  for (int e = tid; e < 4096; e += 256) {
    int r = e >> 6, c = e & 63;
    tile[c][r] = src[(size_t)(t0 + r) * 3072 + c];
  }
  __syncthreads();
  unsigned short* dst = vt + (size_t)bh * 64 * Tx + t0;
  for (int e = tid; e < 4096; e += 256) {
    int d = e >> 6, tt = e & 63;
    dst[(size_t)d * Tx + tt] = tile[d][tt];
  }
}

// ---------------- causal flash attention v2 ---------------------------------------
// grid (16, 64bh), 256 thr = 4 independent waves (no cross-wave sync).
// Wave w of block x owns q-tiles qi = x*4+w and 127-qi (16 rows each) ->
// constant 33 kv-tiles of work per wave (folded triangle, perfect balance).
// Softmax: defer-max (T13, __all ballot) + deferred sum-reduce (epilogue only).
__global__ __launch_bounds__(256) void attn_kernel(const unsigned short* __restrict__ qkv,
                                                   const unsigned short* __restrict__ vt,
                                                   unsigned short* __restrict__ aout)
{
  const int bh = blockIdx.y;
  const int b = bh >> 4, h = bh & 15;
  const int wave = threadIdx.x >> 6, lane = threadIdx.x & 63;
  const int l15 = lane & 15, l4 = lane >> 4;
  const int qi0 = (blockIdx.x << 2) + wave;   // [0,64)

  const unsigned short* qp = qkv + (size_t)b * Tx * 3072 + h * 64;
  const unsigned short* kp = qp + 1024;
  const unsigned short* vp = vt + (size_t)bh * 64 * Tx;
  unsigned short* op = aout + (size_t)b * Tx * 1024 + h * 64;

  __shared__ unsigned short Pl[4][2][16 * 72];   // per-wave, double-buffered by tile parity
  const float SC = 0.125f * 1.44269504f;          // (1/sqrt(64)) * log2(e)

  #pragma unroll 1
  for (int half = 0; half < 2; ++half) {
    const int qi = half ? (127 - qi0) : qi0;
    const int qrow0 = qi << 4;
    const int lastkv = qi >> 2;

    bf16x8 aq0 = *(const bf16x8*)&qp[(size_t)(qrow0 + l15) * 3072 + (l4 << 3)];
    bf16x8 aq1 = *(const bf16x8*)&qp[(size_t)(qrow0 + l15) * 3072 + 32 + (l4 << 3)];

    float m_run[4], rs[4];
    f32x4 oacc[4];
    #pragma unroll
    for (int r = 0; r < 4; ++r) { m_run[r] = 0.f; rs[r] = 0.f; }
    #pragma unroll
    for (int nt = 0; nt < 4; ++nt) { oacc[nt][0]=0.f; oacc[nt][1]=0.f; oacc[nt][2]=0.f; oacc[nt][3]=0.f; }

    for (int kvt = 0; kvt <= lastkv; ++kvt) {
      const int kv0 = kvt << 6;
      // ---- S = Q K^T ----
      f32x4 s[4];
      #pragma unroll
      for (int nt = 0; nt < 4; ++nt) { s[nt][0]=0.f; s[nt][1]=0.f; s[nt][2]=0.f; s[nt][3]=0.f; }
      #pragma unroll
      for (int nt = 0; nt < 4; ++nt) {
        const unsigned short* krow = &kp[(size_t)(kv0 + (nt << 4) + l15) * 3072 + (l4 << 3)];
        bf16x8 bk0 = *(const bf16x8*)krow;
        bf16x8 bk1 = *(const bf16x8*)(krow + 32);
        s[nt] = __builtin_amdgcn_mfma_f32_16x16x32_bf16(aq0, bk0, s[nt], 0, 0, 0);
        s[nt] = __builtin_amdgcn_mfma_f32_16x16x32_bf16(aq1, bk1, s[nt], 0, 0, 0);
      }
      // ---- scale (log2 units) + causal mask on last tile ----
      const bool diag = (kvt == lastkv);
      float pv[4][4];
      #pragma unroll
      for (int nt = 0; nt < 4; ++nt) {
        const int kv = kv0 + (nt << 4) + l15;
        #pragma unroll
        for (int r = 0; r < 4; ++r) {
          float val = s[nt][r] * SC;
          if (diag && kv > qrow0 + (l4 << 2) + r) val = -3.0e38f;
          pv[nt][r] = val;
        }
      }
      // ---- defer-max online softmax ----
      float pm[4];
      #pragma unroll
      for (int r = 0; r < 4; ++r)
        pm[r] = fmaxf(fmaxf(pv[0][r], pv[1][r]), fmaxf(pv[2][r], pv[3][r]));
      int ok = (pm[0] <= m_run[0] + 8.f) & (pm[1] <= m_run[1] + 8.f)
             & (pm[2] <= m_run[2] + 8.f) & (pm[3] <= m_run[3] + 8.f);
      if (!__all(ok)) {   // rare fallback: full reduce + rescale partial state
        #pragma unroll
        for (int off = 1; off < 16; off <<= 1)
          #pragma unroll
          for (int r = 0; r < 4; ++r) pm[r] = fmaxf(pm[r], __shfl_xor(pm[r], off));
        #pragma unroll
        for (int r = 0; r < 4; ++r) {
          float mnew = fmaxf(m_run[r], pm[r]);
          float corr = exp2f(m_run[r] - mnew);
          rs[r] *= corr;
          #pragma unroll
          for (int nt = 0; nt < 4; ++nt) oacc[nt][r] *= corr;
          m_run[r] = mnew;
        }
      }
      #pragma unroll
      for (int nt = 0; nt < 4; ++nt)
        #pragma unroll
        for (int r = 0; r < 4; ++r) {
          float p = exp2f(pv[nt][r] - m_run[r]);
          pv[nt][r] = p;
          rs[r] += p;
        }

      // ---- P -> LDS (wave-local, no barrier), then PV ----
      unsigned short* Plw = Pl[wave][kvt & 1];
      #pragma unroll
      for (int nt = 0; nt < 4; ++nt)
        #pragma unroll
        for (int r = 0; r < 4; ++r)
          Plw[((l4 << 2) + r) * 72 + (nt << 4) + l15] = f2bf(pv[nt][r]);
      asm volatile("s_waitcnt lgkmcnt(0)" ::: "memory");
      __builtin_amdgcn_sched_barrier(0);
      bf16x8 ap0 = *(const bf16x8*)&Plw[l15 * 72 + (l4 << 3)];
      bf16x8 ap1 = *(const bf16x8*)&Plw[l15 * 72 + 32 + (l4 << 3)];
      #pragma unroll
      for (int nt = 0; nt < 4; ++nt) {
        const unsigned short* vrow = &vp[(size_t)((nt << 4) + l15) * Tx + kv0 + (l4 << 3)];
        bf16x8 bv0 = *(const bf16x8*)vrow;
        bf16x8 bv1 = *(const bf16x8*)(vrow + 32);
        oacc[nt] = __builtin_amdgcn_mfma_f32_16x16x32_bf16(ap0, bv0, oacc[nt], 0, 0, 0);
        oacc[nt] = __builtin_amdgcn_mfma_f32_16x16x32_bf16(ap1, bv1, oacc[nt], 0, 0, 0);
      }
    }

    // ---- epilogue: reduce row-sums across the 16 l15-lanes, normalize, store ----
    #pragma unroll
    for (int off = 1; off < 16; off <<= 1)
      #pragma unroll
      for (int r = 0; r < 4; ++r) rs[r] += __shfl_xor(rs[r], off);
    #pragma unroll
    for (int r = 0; r < 4; ++r) {
      const float inv = 1.0f / rs[r];
      #pragma unroll
      for (int nt = 0; nt < 4; ++nt)
        op[(size_t)(qrow0 + (l4 << 2) + r) * 1024 + (nt << 4) + l15] = f2bf(oacc[nt][r] * inv);
    }
  }
}

// ---------------- launch ----------------------------------------------------------
extern "C" void kernel_launch(void* const* d_in, const int* in_sizes, int n_in,
                              void* d_out, int out_size, void* d_ws, size_t ws_size,
                              hipStream_t stream) {
  const float* x     = (const float*)d_in[0];
  const float* wqkv  = (const float*)d_in[1];
  const float* wproj = (const float*)d_in[2];

  char* ws = (char*)d_ws;
  unsigned short* qkvb = (unsigned short*)(ws);
  unsigned short* vtb  = (unsigned short*)(ws + 50331648);
  unsigned short* xb   = (unsigned short*)(ws + 50331648 + 16777216);
  unsigned short* wqb  = (unsigned short*)(ws + 50331648 + 16777216 + 16777216);
  unsigned short* wpb  = (unsigned short*)(ws + 50331648 + 16777216 + 16777216 + 6291456);
  unsigned short* aob  = xb;  // alias: xb dead after GEMM1

  cvt_kernel<<<4096, 256, 0, stream>>>(x,     xb,  Bx * Tx * Cx);
  cvt_kernel<<<1536, 256, 0, stream>>>(wqkv,  wqb, 3 * Cx * Cx);
  cvt_kernel<<<512,  256, 0, stream>>>(wproj, wpb, Cx * Cx);

  gemm_nt<0><<<dim3(24, 64), 256, 0, stream>>>(xb, wqb, qkvb, Mx, 3072, 1024);
  vtrans_kernel<<<dim3(32, 64), 256, 0, stream>>>(qkvb, vtb);
  attn_kernel<<<dim3(16, 64), 256, 0, stream>>>(qkvb, vtb, aob);
  gemm_nt<1><<<dim3(8, 64), 256, 0, stream>>>(aob, wpb, d_out, Mx, 1024, 1024);
}

// Round 3
// 309.517 us; speedup vs baseline: 2.2923x; 1.4489x over previous
//
#include <hip/hip_runtime.h>
#include <hip/hip_bf16.h>
#include <stdint.h>

#define Bx 4
#define Tx 2048
#define Cx 1024
#define Hx 16
#define Dx 64
#define Mx (Bx*Tx)

typedef __bf16 bf16x8 __attribute__((ext_vector_type(8)));
typedef float f32x4 __attribute__((ext_vector_type(4)));
typedef unsigned short u16x8 __attribute__((ext_vector_type(8)));

__device__ __forceinline__ unsigned short f2bf(float f) {
  union { float f; unsigned u; } v; v.f = f;
  unsigned r = v.u + 0x7fffu + ((v.u >> 16) & 1u);
  return (unsigned short)(r >> 16);
}

// ---------------- f32 -> bf16 convert (vectorized, 8 elems/thread) -------------
__global__ void cvt_kernel(const float* __restrict__ in, unsigned short* __restrict__ out, int n) {
  int i = blockIdx.x * blockDim.x + threadIdx.x;
  int idx = i << 3;
  if (idx >= n) return;
  const float4* p = (const float4*)(in + idx);
  float4 a = p[0], b = p[1];
  u16x8 o;
  o[0] = f2bf(a.x); o[1] = f2bf(a.y); o[2] = f2bf(a.z); o[3] = f2bf(a.w);
  o[4] = f2bf(b.x); o[5] = f2bf(b.y); o[6] = f2bf(b.z); o[7] = f2bf(b.w);
  *(u16x8*)(out + idx) = o;
}

// ---------------- NT GEMM: C[M][N] = A[M][K] * B[N][K]^T, bf16 in, f32 acc ------
#define GLOAD_LDS16(g, l) \
  __builtin_amdgcn_global_load_lds((const __attribute__((address_space(1))) void*)(g), \
                                   (__attribute__((address_space(3))) void*)(l), 16, 0, 0)

template<int OUT_F32>
__global__ __launch_bounds__(256) void gemm_nt(const unsigned short* __restrict__ A,
                                               const unsigned short* __restrict__ Bm,
                                               void* __restrict__ Cv,
                                               int M, int N, int K)
{
  __shared__ unsigned short As[128 * 32];
  __shared__ unsigned short Bs[128 * 32];
  const int tid  = threadIdx.x;
  const int wave = tid >> 6, lane = tid & 63;
  const int l15 = lane & 15, l4 = lane >> 4;
  const int mBase = blockIdx.y << 7;
  const int nBase = blockIdx.x << 7;
  const int wm = wave >> 1, wn = wave & 1;

  const int srow  = (wave << 4) + (lane >> 2);
  const int skcol = (lane & 3) << 3;

  f32x4 acc[4][4];
  #pragma unroll
  for (int i = 0; i < 4; ++i)
    #pragma unroll
    for (int j = 0; j < 4; ++j) { acc[i][j][0] = 0.f; acc[i][j][1] = 0.f; acc[i][j][2] = 0.f; acc[i][j][3] = 0.f; }

  const unsigned short* aRow = A  + (size_t)(mBase + srow) * K + skcol;
  const unsigned short* bRow = Bm + (size_t)(nBase + srow) * K + skcol;
  unsigned short* aL0 = As + (wave << 9);
  unsigned short* bL0 = Bs + (wave << 9);

  for (int k0 = 0; k0 < K; k0 += 32) {
    GLOAD_LDS16(aRow + k0,                   aL0);
    GLOAD_LDS16(aRow + (size_t)64 * K + k0,  aL0 + 2048);
    GLOAD_LDS16(bRow + k0,                   bL0);
    GLOAD_LDS16(bRow + (size_t)64 * K + k0,  bL0 + 2048);
    __syncthreads();

    bf16x8 af[4], bfr[4];
    #pragma unroll
    for (int mi = 0; mi < 4; ++mi)
      af[mi] = *(const bf16x8*)&As[((wm << 6) + (mi << 4) + l15) * 32 + (l4 << 3)];
    #pragma unroll
    for (int nj = 0; nj < 4; ++nj)
      bfr[nj] = *(const bf16x8*)&Bs[((wn << 6) + (nj << 4) + l15) * 32 + (l4 << 3)];
    #pragma unroll
    for (int mi = 0; mi < 4; ++mi)
      #pragma unroll
      for (int nj = 0; nj < 4; ++nj)
        acc[mi][nj] = __builtin_amdgcn_mfma_f32_16x16x32_bf16(af[mi], bfr[nj], acc[mi][nj], 0, 0, 0);
    __syncthreads();
  }

  #pragma unroll
  for (int mi = 0; mi < 4; ++mi) {
    #pragma unroll
    for (int nj = 0; nj < 4; ++nj) {
      const int row = mBase + (wm << 6) + (mi << 4) + (l4 << 2);
      const int col = nBase + (wn << 6) + (nj << 4) + l15;
      #pragma unroll
      for (int r = 0; r < 4; ++r) {
        float v = acc[mi][nj][r];
        if (OUT_F32) ((float*)Cv)[(size_t)(row + r) * N + col] = v;
        else ((unsigned short*)Cv)[(size_t)(row + r) * N + col] = f2bf(v);
      }
    }
  }
}

// ---------------- V transpose: qkv[...,2048+h*64+d] -> vt[b,h,d,t] ---------------
__global__ void vtrans_kernel(const unsigned short* __restrict__ qkv, unsigned short* __restrict__ vt) {
  const int bh = blockIdx.y;
  const int b = bh >> 4, h = bh & 15;
  const int t0 = blockIdx.x << 6;
  __shared__ unsigned short tile[64][65];
  const int tid = threadIdx.x;
  const unsigned short* src = qkv + (size_t)b * Tx * 3072 + 2048 + h * 64;
  for (int e = tid; e < 4096; e += 256) {
    int r = e >> 6, c = e & 63;
    tile[c][r] = src[(size_t)(t0 + r) * 3072 + c];
  }
  __syncthreads();
  unsigned short* dst = vt + (size_t)bh * 64 * Tx + t0;
  for (int e = tid; e < 4096; e += 256) {
    int d = e >> 6, tt = e & 63;
    dst[(size_t)d * Tx + tt] = tile[d][tt];
  }
}

// ---------------- causal flash attention v3 ---------------------------------------
// 1D grid 1024 blocks. XCD-aware: xcd = id&7, 8 heads per XCD (K+V = 4MB = L2).
// Block = 4 waves, wave w handles q-tiles qi0=xblk*4+w and 127-qi0 (folded
// triangle). Both halves of ALL 4 waves share identical kv-tile ranges:
//   lastA = xblk (half0), lastB = 31-xblk (half1), lastA < lastB always.
// K,V tiles staged once per block in LDS (global_load_lds w16, XOR-swizzled
// via pre-swizzled global source, G4/m173), consumed by both halves.
__device__ __forceinline__ void compute_half(
    const unsigned short* __restrict__ Ks, const unsigned short* __restrict__ Vs,
    unsigned short* __restrict__ Plw,
    bf16x8 aq0, bf16x8 aq1, float* m_run, float* rs, f32x4* oacc,
    int qrow0, int kv0, bool diag, int l15, int l4)
{
  const float SC = 0.125f * 1.44269504f;
  f32x4 s[4];
  #pragma unroll
  for (int nt = 0; nt < 4; ++nt) { s[nt][0]=0.f; s[nt][1]=0.f; s[nt][2]=0.f; s[nt][3]=0.f; }
  #pragma unroll
  for (int nt = 0; nt < 4; ++nt) {
    const int r = (nt << 4) + l15, sz = r & 7;
    bf16x8 bk0 = *(const bf16x8*)&Ks[r * 64 + ((l4 ^ sz) << 3)];
    bf16x8 bk1 = *(const bf16x8*)&Ks[r * 64 + (((l4 + 4) ^ sz) << 3)];
    s[nt] = __builtin_amdgcn_mfma_f32_16x16x32_bf16(aq0, bk0, s[nt], 0, 0, 0);
    s[nt] = __builtin_amdgcn_mfma_f32_16x16x32_bf16(aq1, bk1, s[nt], 0, 0, 0);
  }
  // scale (log2 units) + causal mask on diag tile
  #pragma unroll
  for (int nt = 0; nt < 4; ++nt) {
    const int kv = kv0 + (nt << 4) + l15;
    #pragma unroll
    for (int r = 0; r < 4; ++r) {
      float val = s[nt][r] * SC;
      if (diag && kv > qrow0 + (l4 << 2) + r) val = -3.0e38f;
      s[nt][r] = val;
    }
  }
  // defer-max online softmax
  float pm[4];
  #pragma unroll
  for (int r = 0; r < 4; ++r)
    pm[r] = fmaxf(fmaxf(s[0][r], s[1][r]), fmaxf(s[2][r], s[3][r]));
  int ok = (pm[0] <= m_run[0] + 8.f) & (pm[1] <= m_run[1] + 8.f)
         & (pm[2] <= m_run[2] + 8.f) & (pm[3] <= m_run[3] + 8.f);
  if (!__all(ok)) {
    #pragma unroll
    for (int off = 1; off < 16; off <<= 1)
      #pragma unroll
      for (int r = 0; r < 4; ++r) pm[r] = fmaxf(pm[r], __shfl_xor(pm[r], off));
    #pragma unroll
    for (int r = 0; r < 4; ++r) {
      float mnew = fmaxf(m_run[r], pm[r]);
      float corr = exp2f(m_run[r] - mnew);
      rs[r] *= corr;
      #pragma unroll
      for (int nt = 0; nt < 4; ++nt) oacc[nt][r] *= corr;
      m_run[r] = mnew;
    }
  }
  #pragma unroll
  for (int nt = 0; nt < 4; ++nt)
    #pragma unroll
    for (int r = 0; r < 4; ++r) {
      float p = exp2f(s[nt][r] - m_run[r]);
      s[nt][r] = p;
      rs[r] += p;
    }
  // P -> LDS (wave-local), then PV
  #pragma unroll
  for (int nt = 0; nt < 4; ++nt)
    #pragma unroll
    for (int r = 0; r < 4; ++r)
      Plw[((l4 << 2) + r) * 72 + (nt << 4) + l15] = f2bf(s[nt][r]);
  asm volatile("s_waitcnt lgkmcnt(0)" ::: "memory");
  __builtin_amdgcn_sched_barrier(0);
  bf16x8 ap0 = *(const bf16x8*)&Plw[l15 * 72 + (l4 << 3)];
  bf16x8 ap1 = *(const bf16x8*)&Plw[l15 * 72 + 32 + (l4 << 3)];
  #pragma unroll
  for (int nt = 0; nt < 4; ++nt) {
    const int r = (nt << 4) + l15, vz = r & 7;
    bf16x8 bv0 = *(const bf16x8*)&Vs[r * 64 + ((l4 ^ vz) << 3)];
    bf16x8 bv1 = *(const bf16x8*)&Vs[r * 64 + (((l4 + 4) ^ vz) << 3)];
    oacc[nt] = __builtin_amdgcn_mfma_f32_16x16x32_bf16(ap0, bv0, oacc[nt], 0, 0, 0);
    oacc[nt] = __builtin_amdgcn_mfma_f32_16x16x32_bf16(ap1, bv1, oacc[nt], 0, 0, 0);
  }
}

__global__ __launch_bounds__(256, 4) void attn_kernel(const unsigned short* __restrict__ qkv,
                                                      const unsigned short* __restrict__ vt,
                                                      unsigned short* __restrict__ aout)
{
  const int id = blockIdx.x;
  const int xcd = id & 7, sblk = id >> 3;
  const int xblk = sblk & 15;
  const int bh = (xcd << 3) + (sblk >> 4);
  const int b = bh >> 4, h = bh & 15;
  const int wave = threadIdx.x >> 6, lane = threadIdx.x & 63;
  const int l15 = lane & 15, l4 = lane >> 4;
  const int qi0 = (xblk << 2) + wave;

  const unsigned short* qp = qkv + (size_t)b * Tx * 3072 + h * 64;
  const unsigned short* kp = qp + 1024;
  const unsigned short* vp = vt + (size_t)bh * 64 * Tx;
  unsigned short* op = aout + (size_t)b * Tx * 1024 + h * 64;

  __shared__ unsigned short Ks[64 * 64];
  __shared__ unsigned short Vs[64 * 64];
  __shared__ unsigned short Pl[4][2][16 * 72];

  const int qiA = qi0, qiB = 127 - qi0;
  const int qrA = qiA << 4, qrB = qiB << 4;
  const int lastA = xblk, lastB = 31 - xblk;

  bf16x8 aqA0 = *(const bf16x8*)&qp[(size_t)(qrA + l15) * 3072 + (l4 << 3)];
  bf16x8 aqA1 = *(const bf16x8*)&qp[(size_t)(qrA + l15) * 3072 + 32 + (l4 << 3)];
  bf16x8 aqB0 = *(const bf16x8*)&qp[(size_t)(qrB + l15) * 3072 + (l4 << 3)];
  bf16x8 aqB1 = *(const bf16x8*)&qp[(size_t)(qrB + l15) * 3072 + 32 + (l4 << 3)];

  float mA[4], rsA[4], mB[4], rsB[4];
  f32x4 oA[4], oB[4];
  #pragma unroll
  for (int r = 0; r < 4; ++r) { mA[r]=0.f; rsA[r]=0.f; mB[r]=0.f; rsB[r]=0.f; }
  #pragma unroll
  for (int nt = 0; nt < 4; ++nt) {
    oA[nt][0]=0.f; oA[nt][1]=0.f; oA[nt][2]=0.f; oA[nt][3]=0.f;
    oB[nt][0]=0.f; oB[nt][1]=0.f; oB[nt][2]=0.f; oB[nt][3]=0.f;
  }

  // staging lane constants: row offset within 8-row chunk, swizzled col chunk
  const int srw = lane >> 3;                 // 0..7
  const int sj  = (lane & 7) ^ srw;          // source chunk = dest ^ (row&7)

  for (int kvt = 0; kvt <= lastB; ++kvt) {
    const int kv0 = kvt << 6;
    // ---- stage K,V tile (each wave: chunks c=2w,2w+1; 8 rows per chunk) ----
    {
      const int c0 = wave << 1, c1 = c0 + 1;
      const int r0 = (c0 << 3) + srw, r1 = (c1 << 3) + srw;
      GLOAD_LDS16(kp + (size_t)(kv0 + r0) * 3072 + (sj << 3), Ks + (c0 << 9));
      GLOAD_LDS16(kp + (size_t)(kv0 + r1) * 3072 + (sj << 3), Ks + (c1 << 9));
      GLOAD_LDS16(vp + (size_t)r0 * 2048 + kv0 + (sj << 3),   Vs + (c0 << 9));
      GLOAD_LDS16(vp + (size_t)r1 * 2048 + kv0 + (sj << 3),   Vs + (c1 << 9));
    }
    __syncthreads();   // drains vmcnt -> staged K/V visible

    compute_half(Ks, Vs, Pl[wave][1], aqB0, aqB1, mB, rsB, oB, qrB, kv0, kvt == lastB, l15, l4);
    if (kvt <= lastA)  // uniform across waves (lastA = xblk)
      compute_half(Ks, Vs, Pl[wave][0], aqA0, aqA1, mA, rsA, oA, qrA, kv0, kvt == lastA, l15, l4);

    __syncthreads();   // protect LDS before next stage
  }

  // ---- epilogue: reduce row-sums across 16 l15-lanes, normalize, store ----
  #pragma unroll
  for (int off = 1; off < 16; off <<= 1)
    #pragma unroll
    for (int r = 0; r < 4; ++r) { rsA[r] += __shfl_xor(rsA[r], off); rsB[r] += __shfl_xor(rsB[r], off); }
  #pragma unroll
  for (int r = 0; r < 4; ++r) {
    const float invA = 1.0f / rsA[r], invB = 1.0f / rsB[r];
    #pragma unroll
    for (int nt = 0; nt < 4; ++nt) {
      op[(size_t)(qrA + (l4 << 2) + r) * 1024 + (nt << 4) + l15] = f2bf(oA[nt][r] * invA);
      op[(size_t)(qrB + (l4 << 2) + r) * 1024 + (nt << 4) + l15] = f2bf(oB[nt][r] * invB);
    }
  }
}

// ---------------- launch ----------------------------------------------------------
extern "C" void kernel_launch(void* const* d_in, const int* in_sizes, int n_in,
                              void* d_out, int out_size, void* d_ws, size_t ws_size,
                              hipStream_t stream) {
  const float* x     = (const float*)d_in[0];
  const float* wqkv  = (const float*)d_in[1];
  const float* wproj = (const float*)d_in[2];

  char* ws = (char*)d_ws;
  unsigned short* qkvb = (unsigned short*)(ws);
  unsigned short* vtb  = (unsigned short*)(ws + 50331648);
  unsigned short* xb   = (unsigned short*)(ws + 50331648 + 16777216);
  unsigned short* wqb  = (unsigned short*)(ws + 50331648 + 16777216 + 16777216);
  unsigned short* wpb  = (unsigned short*)(ws + 50331648 + 16777216 + 16777216 + 6291456);
  unsigned short* aob  = xb;  // alias: xb dead after GEMM1

  cvt_kernel<<<4096, 256, 0, stream>>>(x,     xb,  Bx * Tx * Cx);
  cvt_kernel<<<1536, 256, 0, stream>>>(wqkv,  wqb, 3 * Cx * Cx);
  cvt_kernel<<<512,  256, 0, stream>>>(wproj, wpb, Cx * Cx);

  gemm_nt<0><<<dim3(24, 64), 256, 0, stream>>>(xb, wqb, qkvb, Mx, 3072, 1024);
  vtrans_kernel<<<dim3(32, 64), 256, 0, stream>>>(qkvb, vtb);
  attn_kernel<<<1024, 256, 0, stream>>>(qkvb, vtb, aob);
  gemm_nt<1><<<dim3(8, 64), 256, 0, stream>>>(aob, wpb, d_out, Mx, 1024, 1024);
}

// Round 4
// 298.863 us; speedup vs baseline: 2.3741x; 1.0356x over previous
//
#include <hip/hip_runtime.h>
#include <hip/hip_bf16.h>
#include <stdint.h>

#define Bx 4
#define Tx 2048
#define Cx 1024
#define Hx 16
#define Dx 64
#define Mx (Bx*Tx)

typedef __bf16 bf16x8 __attribute__((ext_vector_type(8)));
typedef float f32x4 __attribute__((ext_vector_type(4)));
typedef unsigned short u16x8 __attribute__((ext_vector_type(8)));

__device__ __forceinline__ unsigned short f2bf(float f) {
  union { float f; unsigned u; } v; v.f = f;
  unsigned r = v.u + 0x7fffu + ((v.u >> 16) & 1u);
  return (unsigned short)(r >> 16);
}

// ---------------- f32 -> bf16 convert (vectorized, 8 elems/thread) -------------
__global__ void cvt_kernel(const float* __restrict__ in, unsigned short* __restrict__ out, int n) {
  int i = blockIdx.x * blockDim.x + threadIdx.x;
  int idx = i << 3;
  if (idx >= n) return;
  const float4* p = (const float4*)(in + idx);
  float4 a = p[0], b = p[1];
  u16x8 o;
  o[0] = f2bf(a.x); o[1] = f2bf(a.y); o[2] = f2bf(a.z); o[3] = f2bf(a.w);
  o[4] = f2bf(b.x); o[5] = f2bf(b.y); o[6] = f2bf(b.z); o[7] = f2bf(b.w);
  *(u16x8*)(out + idx) = o;
}

#define GLOAD_LDS16(g, l) \
  __builtin_amdgcn_global_load_lds((const __attribute__((address_space(1))) void*)(g), \
                                   (__attribute__((address_space(3))) void*)(l), 16, 0, 0)

// ---------------- 8-wave counted-vmcnt NT GEMM -----------------------------------
// C[M][N] = A[M][K] * B[N][K]^T, bf16 in, f32 acc. BM=256 BN=128 BK=64,
// 512 thr = 8 waves (4M x 2N), per-wave 64x64 out. LDS 96KB double-buffered.
// T4: 6 gloads/tile issued one tile ahead, s_waitcnt vmcnt(6) (never 0 in loop).
// T2: linear LDS dest + inverse-swizzled global source chunk (c ^ (row&7)),
//     same XOR on ds_read side -> conflict-free b128 reads.
// T5: setprio(1) around each 16-MFMA cluster.
// Race proof: stages for t+1 write buf (t+1)&1, last read at iter t-1 whose
// end-of-tile barrier precedes iter t's issue; vmcnt(6)+barrier at iter t+1 top
// makes tile-(t+1) data visible to all waves before any read.
template<int OUT_F32>
__global__ __launch_bounds__(512, 1) void gemm8p(const unsigned short* __restrict__ A,
                                                 const unsigned short* __restrict__ Bm,
                                                 void* __restrict__ Cv,
                                                 int M, int N, int K)
{
  __shared__ unsigned short As[2][256 * 64];
  __shared__ unsigned short Bs[2][128 * 64];
  const int tid = threadIdx.x;
  const int wave = tid >> 6, lane = tid & 63;
  const int l15 = lane & 15, l4 = lane >> 4;
  const int wm = wave >> 1, wn = wave & 1;
  const int NB = N >> 7;
  // T1: bijective XCD swizzle (gridDim.x % 8 == 0 at both call sites)
  const int cpx = (int)gridDim.x >> 3;
  const int bid = (int)blockIdx.x;
  const int swz = (bid & 7) * cpx + (bid >> 3);
  const int bx = swz % NB, by = swz / NB;
  const int mBase = by << 8, nBase = bx << 7;

  const int srow   = tid >> 3;                  // row 0..63 within a 64-row stage
  const int schunk = (tid & 7) ^ (srow & 7);    // inverse-swizzled source chunk
  const unsigned short* aSrc = A  + (size_t)(mBase + srow) * K + (schunk << 3);
  const unsigned short* bSrc = Bm + (size_t)(nBase + srow) * K + (schunk << 3);
  const int dstOff = wave << 9;                 // wave-uniform lane-linear dest

  f32x4 acc[4][4];
  #pragma unroll
  for (int i = 0; i < 4; ++i)
    #pragma unroll
    for (int j = 0; j < 4; ++j) { acc[i][j][0]=0.f; acc[i][j][1]=0.f; acc[i][j][2]=0.f; acc[i][j][3]=0.f; }

  const int NT = K >> 6;
  const int s7 = l15 & 7;

#define STAGE6(k0, buf) do { \
    GLOAD_LDS16(aSrc + (k0),                   &As[buf][dstOff]); \
    GLOAD_LDS16(aSrc + (size_t) 64*K + (k0),   &As[buf][ 4096 + dstOff]); \
    GLOAD_LDS16(aSrc + (size_t)128*K + (k0),   &As[buf][ 8192 + dstOff]); \
    GLOAD_LDS16(aSrc + (size_t)192*K + (k0),   &As[buf][12288 + dstOff]); \
    GLOAD_LDS16(bSrc + (k0),                   &Bs[buf][dstOff]); \
    GLOAD_LDS16(bSrc + (size_t) 64*K + (k0),   &Bs[buf][ 4096 + dstOff]); \
  } while (0)

  STAGE6(0, 0);
  for (int t = 0; t < NT; ++t) {
    const int buf = t & 1;
    if (t + 1 < NT) {
      STAGE6((t + 1) << 6, buf ^ 1);
      asm volatile("s_waitcnt vmcnt(6)" ::: "memory");  // tile t's 6 oldest landed
    } else {
      asm volatile("s_waitcnt vmcnt(0)" ::: "memory");
    }
    __builtin_amdgcn_s_barrier();
    asm volatile("" ::: "memory");

    const unsigned short* curA = As[buf];
    const unsigned short* curB = Bs[buf];
    #pragma unroll
    for (int kk = 0; kk < 2; ++kk) {
      const int ch = ((kk << 2) | l4) ^ s7;   // swizzled chunk (row&7 == l15&7)
      bf16x8 af[4], bfr[4];
      #pragma unroll
      for (int mi = 0; mi < 4; ++mi)
        af[mi]  = *(const bf16x8*)&curA[((wm << 6) + (mi << 4) + l15) * 64 + (ch << 3)];
      #pragma unroll
      for (int nj = 0; nj < 4; ++nj)
        bfr[nj] = *(const bf16x8*)&curB[((wn << 6) + (nj << 4) + l15) * 64 + (ch << 3)];
      __builtin_amdgcn_s_setprio(1);
      #pragma unroll
      for (int mi = 0; mi < 4; ++mi)
        #pragma unroll
        for (int nj = 0; nj < 4; ++nj)
          acc[mi][nj] = __builtin_amdgcn_mfma_f32_16x16x32_bf16(af[mi], bfr[nj], acc[mi][nj], 0, 0, 0);
      __builtin_amdgcn_s_setprio(0);
    }
    asm volatile("" ::: "memory");
    __builtin_amdgcn_s_barrier();
  }
#undef STAGE6

  #pragma unroll
  for (int mi = 0; mi < 4; ++mi)
    #pragma unroll
    for (int nj = 0; nj < 4; ++nj) {
      const int row = mBase + (wm << 6) + (mi << 4) + (l4 << 2);
      const int col = nBase + (wn << 6) + (nj << 4) + l15;
      #pragma unroll
      for (int r = 0; r < 4; ++r) {
        float v = acc[mi][nj][r];
        if (OUT_F32) ((float*)Cv)[(size_t)(row + r) * N + col] = v;
        else ((unsigned short*)Cv)[(size_t)(row + r) * N + col] = f2bf(v);
      }
    }
}

// ---------------- V transpose: qkv[...,2048+h*64+d] -> vt[b,h,d,t] ---------------
__global__ void vtrans_kernel(const unsigned short* __restrict__ qkv, unsigned short* __restrict__ vt) {
  const int bh = blockIdx.y;
  const int b = bh >> 4, h = bh & 15;
  const int t0 = blockIdx.x << 6;
  __shared__ unsigned short tile[64][65];
  const int tid = threadIdx.x;
  const unsigned short* src = qkv + (size_t)b * Tx * 3072 + 2048 + h * 64;
  for (int e = tid; e < 4096; e += 256) {
    int r = e >> 6, c = e & 63;
    tile[c][r] = src[(size_t)(t0 + r) * 3072 + c];
  }
  __syncthreads();
  unsigned short* dst = vt + (size_t)bh * 64 * Tx + t0;
  for (int e = tid; e < 4096; e += 256) {
    int d = e >> 6, tt = e & 63;
    dst[(size_t)d * Tx + tt] = tile[d][tt];
  }
}

// ---------------- causal flash attention v3 (unchanged from R3) -------------------
__device__ __forceinline__ void compute_half(
    const unsigned short* __restrict__ Ks, const unsigned short* __restrict__ Vs,
    unsigned short* __restrict__ Plw,
    bf16x8 aq0, bf16x8 aq1, float* m_run, float* rs, f32x4* oacc,
    int qrow0, int kv0, bool diag, int l15, int l4)
{
  const float SC = 0.125f * 1.44269504f;
  f32x4 s[4];
  #pragma unroll
  for (int nt = 0; nt < 4; ++nt) { s[nt][0]=0.f; s[nt][1]=0.f; s[nt][2]=0.f; s[nt][3]=0.f; }
  #pragma unroll
  for (int nt = 0; nt < 4; ++nt) {
    const int r = (nt << 4) + l15, sz = r & 7;
    bf16x8 bk0 = *(const bf16x8*)&Ks[r * 64 + ((l4 ^ sz) << 3)];
    bf16x8 bk1 = *(const bf16x8*)&Ks[r * 64 + (((l4 + 4) ^ sz) << 3)];
    s[nt] = __builtin_amdgcn_mfma_f32_16x16x32_bf16(aq0, bk0, s[nt], 0, 0, 0);
    s[nt] = __builtin_amdgcn_mfma_f32_16x16x32_bf16(aq1, bk1, s[nt], 0, 0, 0);
  }
  #pragma unroll
  for (int nt = 0; nt < 4; ++nt) {
    const int kv = kv0 + (nt << 4) + l15;
    #pragma unroll
    for (int r = 0; r < 4; ++r) {
      float val = s[nt][r] * SC;
      if (diag && kv > qrow0 + (l4 << 2) + r) val = -3.0e38f;
      s[nt][r] = val;
    }
  }
  float pm[4];
  #pragma unroll
  for (int r = 0; r < 4; ++r)
    pm[r] = fmaxf(fmaxf(s[0][r], s[1][r]), fmaxf(s[2][r], s[3][r]));
  int ok = (pm[0] <= m_run[0] + 8.f) & (pm[1] <= m_run[1] + 8.f)
         & (pm[2] <= m_run[2] + 8.f) & (pm[3] <= m_run[3] + 8.f);
  if (!__all(ok)) {
    #pragma unroll
    for (int off = 1; off < 16; off <<= 1)
      #pragma unroll
      for (int r = 0; r < 4; ++r) pm[r] = fmaxf(pm[r], __shfl_xor(pm[r], off));
    #pragma unroll
    for (int r = 0; r < 4; ++r) {
      float mnew = fmaxf(m_run[r], pm[r]);
      float corr = exp2f(m_run[r] - mnew);
      rs[r] *= corr;
      #pragma unroll
      for (int nt = 0; nt < 4; ++nt) oacc[nt][r] *= corr;
      m_run[r] = mnew;
    }
  }
  #pragma unroll
  for (int nt = 0; nt < 4; ++nt)
    #pragma unroll
    for (int r = 0; r < 4; ++r) {
      float p = exp2f(s[nt][r] - m_run[r]);
      s[nt][r] = p;
      rs[r] += p;
    }
  #pragma unroll
  for (int nt = 0; nt < 4; ++nt)
    #pragma unroll
    for (int r = 0; r < 4; ++r)
      Plw[((l4 << 2) + r) * 72 + (nt << 4) + l15] = f2bf(s[nt][r]);
  asm volatile("s_waitcnt lgkmcnt(0)" ::: "memory");
  __builtin_amdgcn_sched_barrier(0);
  bf16x8 ap0 = *(const bf16x8*)&Plw[l15 * 72 + (l4 << 3)];
  bf16x8 ap1 = *(const bf16x8*)&Plw[l15 * 72 + 32 + (l4 << 3)];
  #pragma unroll
  for (int nt = 0; nt < 4; ++nt) {
    const int r = (nt << 4) + l15, vz = r & 7;
    bf16x8 bv0 = *(const bf16x8*)&Vs[r * 64 + ((l4 ^ vz) << 3)];
    bf16x8 bv1 = *(const bf16x8*)&Vs[r * 64 + (((l4 + 4) ^ vz) << 3)];
    oacc[nt] = __builtin_amdgcn_mfma_f32_16x16x32_bf16(ap0, bv0, oacc[nt], 0, 0, 0);
    oacc[nt] = __builtin_amdgcn_mfma_f32_16x16x32_bf16(ap1, bv1, oacc[nt], 0, 0, 0);
  }
}

__global__ __launch_bounds__(256, 4) void attn_kernel(const unsigned short* __restrict__ qkv,
                                                      const unsigned short* __restrict__ vt,
                                                      unsigned short* __restrict__ aout)
{
  const int id = blockIdx.x;
  const int xcd = id & 7, sblk = id >> 3;
  const int xblk = sblk & 15;
  const int bh = (xcd << 3) + (sblk >> 4);
  const int b = bh >> 4, h = bh & 15;
  const int wave = threadIdx.x >> 6, lane = threadIdx.x & 63;
  const int l15 = lane & 15, l4 = lane >> 4;
  const int qi0 = (xblk << 2) + wave;

  const unsigned short* qp = qkv + (size_t)b * Tx * 3072 + h * 64;
  const unsigned short* kp = qp + 1024;
  const unsigned short* vp = vt + (size_t)bh * 64 * Tx;
  unsigned short* op = aout + (size_t)b * Tx * 1024 + h * 64;

  __shared__ unsigned short Ks[64 * 64];
  __shared__ unsigned short Vs[64 * 64];
  __shared__ unsigned short Pl[4][2][16 * 72];

  const int qiA = qi0, qiB = 127 - qi0;
  const int qrA = qiA << 4, qrB = qiB << 4;
  const int lastA = xblk, lastB = 31 - xblk;

  bf16x8 aqA0 = *(const bf16x8*)&qp[(size_t)(qrA + l15) * 3072 + (l4 << 3)];
  bf16x8 aqA1 = *(const bf16x8*)&qp[(size_t)(qrA + l15) * 3072 + 32 + (l4 << 3)];
  bf16x8 aqB0 = *(const bf16x8*)&qp[(size_t)(qrB + l15) * 3072 + (l4 << 3)];
  bf16x8 aqB1 = *(const bf16x8*)&qp[(size_t)(qrB + l15) * 3072 + 32 + (l4 << 3)];

  float mA[4], rsA[4], mB[4], rsB[4];
  f32x4 oA[4], oB[4];
  #pragma unroll
  for (int r = 0; r < 4; ++r) { mA[r]=0.f; rsA[r]=0.f; mB[r]=0.f; rsB[r]=0.f; }
  #pragma unroll
  for (int nt = 0; nt < 4; ++nt) {
    oA[nt][0]=0.f; oA[nt][1]=0.f; oA[nt][2]=0.f; oA[nt][3]=0.f;
    oB[nt][0]=0.f; oB[nt][1]=0.f; oB[nt][2]=0.f; oB[nt][3]=0.f;
  }

  const int srw = lane >> 3;
  const int sj  = (lane & 7) ^ srw;

  for (int kvt = 0; kvt <= lastB; ++kvt) {
    const int kv0 = kvt << 6;
    {
      const int c0 = wave << 1, c1 = c0 + 1;
      const int r0 = (c0 << 3) + srw, r1 = (c1 << 3) + srw;
      GLOAD_LDS16(kp + (size_t)(kv0 + r0) * 3072 + (sj << 3), Ks + (c0 << 9));
      GLOAD_LDS16(kp + (size_t)(kv0 + r1) * 3072 + (sj << 3), Ks + (c1 << 9));
      GLOAD_LDS16(vp + (size_t)r0 * 2048 + kv0 + (sj << 3),   Vs + (c0 << 9));
      GLOAD_LDS16(vp + (size_t)r1 * 2048 + kv0 + (sj << 3),   Vs + (c1 << 9));
    }
    __syncthreads();

    compute_half(Ks, Vs, Pl[wave][1], aqB0, aqB1, mB, rsB, oB, qrB, kv0, kvt == lastB, l15, l4);
    if (kvt <= lastA)
      compute_half(Ks, Vs, Pl[wave][0], aqA0, aqA1, mA, rsA, oA, qrA, kv0, kvt == lastA, l15, l4);

    __syncthreads();
  }

  #pragma unroll
  for (int off = 1; off < 16; off <<= 1)
    #pragma unroll
    for (int r = 0; r < 4; ++r) { rsA[r] += __shfl_xor(rsA[r], off); rsB[r] += __shfl_xor(rsB[r], off); }
  #pragma unroll
  for (int r = 0; r < 4; ++r) {
    const float invA = 1.0f / rsA[r], invB = 1.0f / rsB[r];
    #pragma unroll
    for (int nt = 0; nt < 4; ++nt) {
      op[(size_t)(qrA + (l4 << 2) + r) * 1024 + (nt << 4) + l15] = f2bf(oA[nt][r] * invA);
      op[(size_t)(qrB + (l4 << 2) + r) * 1024 + (nt << 4) + l15] = f2bf(oB[nt][r] * invB);
    }
  }
}

// ---------------- launch ----------------------------------------------------------
extern "C" void kernel_launch(void* const* d_in, const int* in_sizes, int n_in,
                              void* d_out, int out_size, void* d_ws, size_t ws_size,
                              hipStream_t stream) {
  const float* x     = (const float*)d_in[0];
  const float* wqkv  = (const float*)d_in[1];
  const float* wproj = (const float*)d_in[2];

  char* ws = (char*)d_ws;
  unsigned short* qkvb = (unsigned short*)(ws);
  unsigned short* vtb  = (unsigned short*)(ws + 50331648);
  unsigned short* xb   = (unsigned short*)(ws + 50331648 + 16777216);
  unsigned short* wqb  = (unsigned short*)(ws + 50331648 + 16777216 + 16777216);
  unsigned short* wpb  = (unsigned short*)(ws + 50331648 + 16777216 + 16777216 + 6291456);
  unsigned short* aob  = xb;  // alias: xb dead after GEMM1

  cvt_kernel<<<4096, 256, 0, stream>>>(x,     xb,  Bx * Tx * Cx);
  cvt_kernel<<<1536, 256, 0, stream>>>(wqkv,  wqb, 3 * Cx * Cx);
  cvt_kernel<<<512,  256, 0, stream>>>(wproj, wpb, Cx * Cx);

  gemm8p<0><<<dim3(768), 512, 0, stream>>>(xb, wqb, qkvb, Mx, 3072, 1024);
  vtrans_kernel<<<dim3(32, 64), 256, 0, stream>>>(qkvb, vtb);
  attn_kernel<<<1024, 256, 0, stream>>>(qkvb, vtb, aob);
  gemm8p<1><<<dim3(256), 512, 0, stream>>>(aob, wpb, d_out, Mx, 1024, 1024);
}